// Round 3
// baseline (299.688 us; speedup 1.0000x reference)
//
#include <hip/hip_runtime.h>
#include <hip/hip_bf16.h>

typedef _Float16 v8h __attribute__((ext_vector_type(8)));
typedef _Float16 v4h __attribute__((ext_vector_type(4)));
typedef _Float16 v2h __attribute__((ext_vector_type(2)));
typedef float    v4f __attribute__((ext_vector_type(4)));

#define NTOT  16384
#define NN    70
#define STEPS 5
#define TPB   64                     // ONE wave per block; one graph per block
#define NBLK  NTOT                   // 16384 blocks
#define CATN  32                     // cat node stride (halves); octet XOR-swizzled
#define CATH  (80*CATN)              // 2560 halves
#define USTR  232                    // U col stride (halves): 116 dw == 20 mod 32
#define UH    (10*USTR)              // 2320 halves (10 real cols; phantom-col frag
                                     // reads for c>=10 land in cat[]: finite, discarded)

// epilogue weights (fp32, global scalar loads)
#define PWO1 0                       // 10 rows x 12: [Wo1[s][0..9], ann_coef, bo1[s]]
#define PWO2 120
#define PBO2 130
#define NWP  132

// fp16 fragment images (built by prep):
//  [0..1023]     P1 B-frags Wstack, 2 tiles:  nt*512 + lane*8 + j
//  [1024..2047]  P3 A-frags Wr | Wz:          mt*512 + lane*8 + j
//  [2048..2559]  P3 A-frag  Wh:               lane*8 + j
//  [2560..20479] adjacency frags:             2560 + (mt*7+kt)*512 + lane*8 + j
//  NOTE: A-frag image of M == B-frag image of M^T for 16x16x32 (identical
//  (lane,j)->(row/col,k) map), so adjacency images serve as swapped-P2's B operand.
#define OFR  1024
#define OFZ  1536
#define OFH  2048
#define OFA  2560
#define NWF  20480
#define PREPB 40

__device__ __align__(16) float    g_w[NWP];
__device__ __align__(16) _Float16 g_wf[NWF];
__device__ int g_flag;

__device__ __forceinline__ float fast_sigmoid(float x) {
    return __builtin_amdgcn_rcpf(1.0f + __expf(-x));
}
__device__ __forceinline__ float fast_tanh(float x) {
    float ax = fabsf(x);
    float e  = __expf(-2.0f * ax);
    float t  = (1.0f - e) * __builtin_amdgcn_rcpf(1.0f + e);
    return copysignf(t, x);
}

// cat octet swizzle: stride 32 halves (64 B) alone is an 8-way bank conflict on
// 16-lane b128 reads (all even nodes hit banks 0-3). XOR the octet index with
// (node^(node>>2))&3 -> starts spread over 4 slots, 2-way max (free, m136).
// k-layout inside a row is UNCHANGED (k0..9 a_in, k16..25 prop, k26 = 1), so
// prep's weight fragment images are untouched.
__device__ __forceinline__ int cat_off(int node, int k) {
    const int sw = (node ^ (node >> 2)) & 3;
    return node*CATN + (((k >> 3) ^ sw) << 3) + (k & 7);
}

struct __align__(16) Smem {
    _Float16 U[UH];      // 4640 B: U[col=s][k=e*72+node]
    _Float16 cat[CATH];  // 5120 B: swizzled cat[node][k]
};
// 9760 B -> 10240 B alloc: 16 blocks/CU if VGPR <= 128 (LDS-capped)

// ---- prep: probe dtype; build epilogue weights + all fp16 fragment images ----
__global__ void prep_kernel(const void* annv, const void* Av,
    const void* winv, const void* binv, const void* wrv, const void* brv,
    const void* wzv, const void* bzv, const void* whv, const void* bhv,
    const void* wo1v, const void* bo1v, const void* wo2v, const void* bo2v)
{
    __shared__ int sflag;
    if (threadIdx.x == 0) {
        const unsigned short* u = (const unsigned short*)annv;
        int good = 0;
        for (int k = 0; k < 128; ++k) {
            unsigned short bb = u[k];
            int ex = (bb >> 7) & 0xFF;
            if (bb == 0 || (ex >= 101 && ex <= 131)) ++good;
        }
        sflag = (good >= 112) ? 1 : 0;
        if (blockIdx.x == 0) g_flag = sflag;
    }
    __syncthreads();
    const int f = sflag;
    #define RD(p, i) (f ? (float)((const __hip_bfloat16*)(p))[i] : ((const float*)(p))[i])
    const int tid = threadIdx.x;
    if (blockIdx.x == 0) {
        for (int idx = tid; idx < 120; idx += blockDim.x) {
            const int s = idx / 12, cc = idx - s*12;
            g_w[PWO1 + idx] = (cc < 11) ? RD(wo1v, s*11 + cc) : RD(bo1v, s);
        }
        for (int idx = tid; idx < 10; idx += blockDim.x) g_w[PWO2 + idx] = RD(wo2v, idx);
        if (tid == 0) { g_w[PBO2] = RD(bo2v, 0); g_w[PBO2+1] = 0.f; }
    }
    for (int idx = blockIdx.x*blockDim.x + tid; idx < NWF; idx += gridDim.x*blockDim.x) {
        float val = 0.f;
        if (idx < OFR) {
            // P1 B-frag: B[k][col=(e,s)]; k 16..25 -> Win[e][s][k-16], k 26 -> b_in
            const int nt = idx >> 9, rem = idx & 511, lane = rem >> 3, j = rem & 7;
            const int k = ((lane >> 4) << 3) + j, col = nt*16 + (lane & 15);
            if (col < 30) {
                const int e = col / 10, s = col - e*10;
                if (k >= 16 && k < 26) val = RD(winv, e*100 + s*10 + (k-16));
                else if (k == 26)      val = RD(binv, e*10 + s);
            }
        } else if (idx < OFH) {
            // P3 A-frags Wr/Wz: A[row=s][k]; k<10 -> W[s][k], 16..25 -> W[s][10+..], 26 -> bias
            const int i2 = idx - OFR;
            const int mt = i2 >> 9, rem = i2 & 511, lane = rem >> 3, j = rem & 7;
            const int k = ((lane >> 4) << 3) + j, s = lane & 15;
            if (s < 10) {
                const void* Wv = mt ? wzv : wrv;
                const void* bv = mt ? bzv : brv;
                if (k < 10)                 val = RD(Wv, s*20 + k);
                else if (k >= 16 && k < 26) val = RD(Wv, s*20 + 10 + (k-16));
                else if (k == 26)           val = RD(bv, s);
            }
        } else if (idx < OFA) {
            const int i2 = idx - OFH;
            const int lane = i2 >> 3, j = i2 & 7;
            const int k = ((lane >> 4) << 3) + j, s = lane & 15;
            if (s < 10) {
                if (k < 10)                 val = RD(whv, s*20 + k);
                else if (k >= 16 && k < 26) val = RD(whv, s*20 + 10 + (k-16));
                else if (k == 26)           val = RD(bhv, s);
            }
        } else {
            // adjacency frag: A[m=node][k=e*72+mm]; zero at pads
            const int i2 = idx - OFA;
            const int w = i2 / 3584, rem = i2 - w*3584;
            const int kt = rem >> 9, r2 = rem & 511, lane = r2 >> 3, j = r2 & 7;
            const int m = w*16 + (lane & 15);
            const int k = kt*32 + ((lane >> 4) << 3) + j;
            const int e = k / 72, mm = k - e*72;
            if (m < NN && e < 3 && mm < NN) val = RD(Av, m*210 + e*70 + mm);
        }
        g_wf[idx] = (_Float16)val;
    }
    #undef RD
}

template<typename T>
__device__ __forceinline__ void run_impl(const void* annv, void* outv, Smem& sm)
{
    const T* ann_g = (const T*)annv;
    T* out_g       = (T*)outv;
    const int lane = threadIdx.x;    // single wave
    const int blk  = blockIdx.x;     // == graph id
    const int q    = lane >> 4;
    const int c    = lane & 15;
    const float* __restrict__ gw = g_w;

    // ---- zero LDS (phantom rows/cols + U pads MUST be finite-zero)
    {
        const int4 zz = {0,0,0,0};
        int4* z = (int4*)&sm;
        #pragma unroll 4
        for (int i = lane; i < (int)(sizeof(Smem)/16); i += TPB) z[i] = zz;
    }
    __syncthreads();

    // ---- seed: prop[0]=ann at k=16, bias-one at k=26
    for (int n2 = lane; n2 < NN; n2 += TPB) {
        sm.cat[cat_off(n2, 16)] = (_Float16)(float)ann_g[blk*NN + n2];
        sm.cat[cat_off(n2, 26)] = (_Float16)1.0f;
    }
    __syncthreads();

    // ---- P1: ins(prop) -> U
    #define PHASE1() do {                                                        \
        const v8h w1f0 = *(const v8h*)&g_wf[      lane*8];                       \
        const v8h w1f1 = *(const v8h*)&g_wf[512 + lane*8];                       \
        _Pragma("unroll")                                                        \
        for (int mt = 0; mt < 5; ++mt) {                                         \
            const v8h af = *(const v8h*)&sm.cat[cat_off(mt*16 + c, q*8)];        \
            const int node0 = mt*16 + q*4;                                       \
            _Pragma("unroll")                                                    \
            for (int nt = 0; nt < 2; ++nt) {                                     \
                v4f acc = {0.f,0.f,0.f,0.f};                                     \
                acc = __builtin_amdgcn_mfma_f32_16x16x32_f16(                    \
                        af, nt ? w1f1 : w1f0, acc, 0,0,0);                       \
                const int colw = nt*16 + c;                                      \
                if (colw < 30 && node0 <= 68) {                                  \
                    const int e = colw / 10, s = colw - e*10;                    \
                    v4h hv = {(_Float16)acc[0],(_Float16)acc[1],                 \
                              (_Float16)acc[2],(_Float16)acc[3]};                \
                    *(v4h*)&sm.U[s*USTR + e*72 + node0] = hv;                    \
                }                                                                \
            }                                                                    \
        }                                                                        \
    } while(0)

    PHASE1();
    __syncthreads();

    #pragma unroll 1
    for (int step = 0; step < STEPS; ++step) {
        // ---- P2 (operand-swapped, software-pipelined adjacency prefetch) ----
        // r2 lesson: use-site adjacency loads (35 x ~200cy L2-hit, g_wf's 35KB
        // adjacency > 32KB L1) serialized into the MFMA chain = +32k cy/block.
        // Fix: distance-2 double-buffer (pa/pb, 56 VGPR), 5 explicit stanzas
        // (compile-time indices only), sched_barrier(0) pins prefetch distance.
        {
            const _Float16* adjb = &g_wf[OFA + lane*8];
            v8h pa[7], pb[7];
            #pragma unroll
            for (int kt = 0; kt < 7; ++kt) pa[kt] = *(const v8h*)(adjb + (0*7+kt)*512);
            #pragma unroll
            for (int kt = 0; kt < 7; ++kt) pb[kt] = *(const v8h*)(adjb + (1*7+kt)*512);
            v8h bfr[7];
            #pragma unroll
            for (int kt = 0; kt < 7; ++kt)
                bfr[kt] = *(const v8h*)&sm.U[c*USTR + q*8 + kt*32];

            #define P2_STORE(mtt, acc) do {                                      \
                const int node = (mtt)*16 + c;                                   \
                if (node < NN) {                                                 \
                    const v4h hv = {(_Float16)acc[0],(_Float16)acc[1],           \
                                    (_Float16)acc[2],(_Float16)acc[3]};          \
                    if (q < 2)       *(v4h*)&sm.cat[cat_off(node, q*4)] = hv;    \
                    else if (q == 2) *(v2h*)&sm.cat[cat_off(node, 8)]            \
                                         = (v2h){hv[0], hv[1]};                  \
                } } while(0)

            // stanza 0: compute mt0 from pa, then prefetch mt2 -> pa
            { v4f acc = {0.f,0.f,0.f,0.f};
              #pragma unroll
              for (int kt = 0; kt < 7; ++kt)
                  acc = __builtin_amdgcn_mfma_f32_16x16x32_f16(bfr[kt], pa[kt], acc, 0,0,0);
              P2_STORE(0, acc);
              __builtin_amdgcn_sched_barrier(0);
              #pragma unroll
              for (int kt = 0; kt < 7; ++kt) pa[kt] = *(const v8h*)(adjb + (2*7+kt)*512);
            }
            // stanza 1: compute mt1 from pb, prefetch mt3 -> pb
            { v4f acc = {0.f,0.f,0.f,0.f};
              #pragma unroll
              for (int kt = 0; kt < 7; ++kt)
                  acc = __builtin_amdgcn_mfma_f32_16x16x32_f16(bfr[kt], pb[kt], acc, 0,0,0);
              P2_STORE(1, acc);
              __builtin_amdgcn_sched_barrier(0);
              #pragma unroll
              for (int kt = 0; kt < 7; ++kt) pb[kt] = *(const v8h*)(adjb + (3*7+kt)*512);
            }
            // stanza 2: compute mt2 from pa, prefetch mt4 -> pa
            { v4f acc = {0.f,0.f,0.f,0.f};
              #pragma unroll
              for (int kt = 0; kt < 7; ++kt)
                  acc = __builtin_amdgcn_mfma_f32_16x16x32_f16(bfr[kt], pa[kt], acc, 0,0,0);
              P2_STORE(2, acc);
              __builtin_amdgcn_sched_barrier(0);
              #pragma unroll
              for (int kt = 0; kt < 7; ++kt) pa[kt] = *(const v8h*)(adjb + (4*7+kt)*512);
            }
            // stanza 3: compute mt3 from pb
            { v4f acc = {0.f,0.f,0.f,0.f};
              #pragma unroll
              for (int kt = 0; kt < 7; ++kt)
                  acc = __builtin_amdgcn_mfma_f32_16x16x32_f16(bfr[kt], pb[kt], acc, 0,0,0);
              P2_STORE(3, acc);
              __builtin_amdgcn_sched_barrier(0);
            }
            // stanza 4: compute mt4 from pa
            { v4f acc = {0.f,0.f,0.f,0.f};
              #pragma unroll
              for (int kt = 0; kt < 7; ++kt)
                  acc = __builtin_amdgcn_mfma_f32_16x16x32_f16(bfr[kt], pa[kt], acc, 0,0,0);
              P2_STORE(4, acc);
            }
            #undef P2_STORE
        }
        __syncthreads();   // a_in visible

        // ---- P3 phase A: r,z + rp-write for ALL 5 node-tiles, one fence
        v4h zgp[5], pgp[5];
        {
            const v8h wrf = *(const v8h*)&g_wf[OFR + lane*8];
            const v8h wzf = *(const v8h*)&g_wf[OFZ + lane*8];
            #pragma unroll
            for (int nt = 0; nt < 5; ++nt) {
                const int node = nt*16 + c;
                const v8h bf = *(const v8h*)&sm.cat[cat_off(node, q*8)];
                v4f ar = {0.f,0.f,0.f,0.f}, az = {0.f,0.f,0.f,0.f};
                ar = __builtin_amdgcn_mfma_f32_16x16x32_f16(wrf, bf, ar, 0,0,0);
                az = __builtin_amdgcn_mfma_f32_16x16x32_f16(wzf, bf, az, 0,0,0);
                const v4h pv = *(const v4h*)&sm.cat[cat_off(node, 16 + q*4)];
                v4h rp, zh;
                #pragma unroll
                for (int i = 0; i < 4; ++i) {
                    const float p = (float)pv[i];
                    zh[i] = (_Float16)fast_sigmoid(az[i]);
                    rp[i] = (_Float16)(fast_sigmoid(ar[i]) * p);
                }
                zgp[nt] = zh; pgp[nt] = pv;
                if (node < NN) {
                    if (q < 2)       *(v4h*)&sm.cat[cat_off(node, 16 + q*4)] = rp;
                    else if (q == 2) *(v2h*)&sm.cat[cat_off(node, 24)] = (v2h){rp[0], rp[1]};
                }
            }
        }
        __syncthreads();   // rp visible cross-lane

        // ---- P3 phase B: h + state update for ALL 5 node-tiles
        {
            const v8h whf = *(const v8h*)&g_wf[OFH + lane*8];
            #pragma unroll
            for (int nt = 0; nt < 5; ++nt) {
                const int node = nt*16 + c;
                const v8h bf2 = *(const v8h*)&sm.cat[cat_off(node, q*8)];
                v4f ah = {0.f,0.f,0.f,0.f};
                ah = __builtin_amdgcn_mfma_f32_16x16x32_f16(whf, bf2, ah, 0,0,0);
                v4h pn;
                #pragma unroll
                for (int i = 0; i < 4; ++i) {
                    const float hh = fast_tanh(ah[i]);
                    const float p  = (float)pgp[nt][i];
                    const float z  = (float)zgp[nt][i];
                    pn[i] = (_Float16)(p + z*(hh - p));
                }
                if (node < NN) {
                    if (q < 2)       *(v4h*)&sm.cat[cat_off(node, 16 + q*4)] = pn;
                    else if (q == 2) *(v2h*)&sm.cat[cat_off(node, 24)] = (v2h){pn[0], pn[1]};
                }
            }
        }
        __syncthreads();   // new prop visible

        // ---- P1 for next step
        if (step < STEPS-1) {
            PHASE1();
            __syncthreads();
        }
    }
    #undef PHASE1

    // ---- epilogue: one output per node
    for (int n2 = lane; n2 < NN; n2 += TPB) {
        const v8h p8 = *(const v8h*)&sm.cat[cat_off(n2, 16)];
        const v2h p2 = *(const v2h*)&sm.cat[cat_off(n2, 24)];
        float pr[10];
        #pragma unroll
        for (int i = 0; i < 8; ++i) pr[i] = (float)p8[i];
        pr[8] = (float)p2[0]; pr[9] = (float)p2[1];
        const float av = (float)ann_g[blk*NN + n2];
        float o = gw[PBO2];
        #pragma unroll
        for (int s = 0; s < 10; ++s) {
            const float* wr_ = &gw[PWO1 + s*12];
            float acc = wr_[11] + wr_[10]*av;
            #pragma unroll
            for (int d = 0; d < 10; ++d) acc += pr[d]*wr_[d];
            o += fast_tanh(acc) * gw[PWO2 + s];
        }
        out_g[blk*NN + n2] = (T)o;
    }
}

// min-waves=2 (cap 256). Target VGPR <= 128 so LDS (10240 B -> 16 blocks/CU)
// stays binding; peak live set ~ bfr28 + pa/pb56 + misc ~= 120.
// r1 lesson: min-waves=4 squeezes to the 64-VGPR tier and SPILLS (+23MB
// scratch traffic). Keep 2. Tripwire: WRITE_SIZE >> 4.9MB => spill.
__global__ __launch_bounds__(TPB, 2)
void ggnn_kernel(const void* annv, void* outv)
{
    __shared__ Smem sm;
    if (g_flag)
        run_impl<__hip_bfloat16>(annv, outv, sm);
    else
        run_impl<float>(annv, outv, sm);
}

extern "C" void kernel_launch(void* const* d_in, const int* in_sizes, int n_in,
                              void* d_out, int out_size, void* d_ws, size_t ws_size,
                              hipStream_t stream) {
    (void)in_sizes; (void)n_in; (void)out_size; (void)d_ws; (void)ws_size;
    hipLaunchKernelGGL(prep_kernel, dim3(PREPB), dim3(256), 0, stream,
        d_in[0], d_in[1], d_in[2], d_in[3], d_in[4], d_in[5], d_in[6],
        d_in[7], d_in[8], d_in[9], d_in[10], d_in[11], d_in[12], d_in[13]);
    hipLaunchKernelGGL(ggnn_kernel, dim3(NBLK), dim3(TPB), 0, stream,
        d_in[0], d_out);
}

// Round 4
// 267.485 us; speedup vs baseline: 1.1204x; 1.1204x over previous
//
#include <hip/hip_runtime.h>
#include <hip/hip_bf16.h>

typedef _Float16 v8h __attribute__((ext_vector_type(8)));
typedef _Float16 v4h __attribute__((ext_vector_type(4)));
typedef _Float16 v2h __attribute__((ext_vector_type(2)));
typedef float    v4f __attribute__((ext_vector_type(4)));

#define NTOT  16384
#define NN    70
#define STEPS 5
#define TPB   64                     // ONE wave per block; one graph per block
#define NBLK  NTOT                   // 16384 blocks
#define CATN  40                     // cat node stride (halves)  [r0 layout]
#define CATH  3208                   // cat total halves (80 nodes * 40 + pad)
#define USTR  232                    // U col stride (halves): 116 dw == 20 mod 32
#define UH    (16*USTR)              // 3712 halves (cols 10..15 phantom-zero)

// epilogue weights (fp32, global scalar loads)
#define PWO1 0                       // 10 rows x 12: [Wo1[s][0..9], ann_coef, bo1[s]]
#define PWO2 120
#define PBO2 130
#define NWP  132

// fp16 fragment images (built by prep):
//  [0..1023]     P1 B-frags Wstack, 2 tiles:  nt*512 + lane*8 + j
//  [1024..2047]  P3 A-frags Wr | Wz:          mt*512 + lane*8 + j
//  [2048..2559]  P3 A-frag  Wh:               lane*8 + j
//  [2560..20479] adjacency frags:             2560 + (mt*7+kt)*512 + lane*8 + j
//  NOTE: A-frag image of M == B-frag image of M^T for 16x16x32 (identical
//  (lane,j)->(row/col,k) map), so adjacency images serve as swapped-P2's B operand.
#define OFR  1024
#define OFZ  1536
#define OFH  2048
#define OFA  2560
#define NWF  20480
#define PREPB 40

__device__ __align__(16) float    g_w[NWP];
__device__ __align__(16) _Float16 g_wf[NWF];
__device__ int g_flag;

__device__ __forceinline__ float fast_sigmoid(float x) {
    return __builtin_amdgcn_rcpf(1.0f + __expf(-x));
}
__device__ __forceinline__ float fast_tanh(float x) {
    float ax = fabsf(x);
    float e  = __expf(-2.0f * ax);
    float t  = (1.0f - e) * __builtin_amdgcn_rcpf(1.0f + e);
    return copysignf(t, x);
}

struct __align__(16) Smem {
    _Float16 U[UH];      // 7424 B: U[col=s][k=e*72+node]
    _Float16 cat[CATH];  // 6416 B: cat[node][k]; k0..9=a_in, 16..25=prop, 26=1
};
// 13840 B -> 14336 alloc: 11 blocks/CU. MEASURED BEST residency point (r0).
// r2/r3 lesson: shrinking LDS to 14-16 blocks/CU made things WORSE (213->229
// ->244 us) -- occupancy is anti-correlated here; per-block latency rules.

// ---- prep: probe dtype; build epilogue weights + all fp16 fragment images ----
__global__ void prep_kernel(const void* annv, const void* Av,
    const void* winv, const void* binv, const void* wrv, const void* brv,
    const void* wzv, const void* bzv, const void* whv, const void* bhv,
    const void* wo1v, const void* bo1v, const void* wo2v, const void* bo2v)
{
    __shared__ int sflag;
    if (threadIdx.x == 0) {
        const unsigned short* u = (const unsigned short*)annv;
        int good = 0;
        for (int k = 0; k < 128; ++k) {
            unsigned short bb = u[k];
            int ex = (bb >> 7) & 0xFF;
            if (bb == 0 || (ex >= 101 && ex <= 131)) ++good;
        }
        sflag = (good >= 112) ? 1 : 0;
        if (blockIdx.x == 0) g_flag = sflag;
    }
    __syncthreads();
    const int f = sflag;
    #define RD(p, i) (f ? (float)((const __hip_bfloat16*)(p))[i] : ((const float*)(p))[i])
    const int tid = threadIdx.x;
    if (blockIdx.x == 0) {
        for (int idx = tid; idx < 120; idx += blockDim.x) {
            const int s = idx / 12, cc = idx - s*12;
            g_w[PWO1 + idx] = (cc < 11) ? RD(wo1v, s*11 + cc) : RD(bo1v, s);
        }
        for (int idx = tid; idx < 10; idx += blockDim.x) g_w[PWO2 + idx] = RD(wo2v, idx);
        if (tid == 0) { g_w[PBO2] = RD(bo2v, 0); g_w[PBO2+1] = 0.f; }
    }
    for (int idx = blockIdx.x*blockDim.x + tid; idx < NWF; idx += gridDim.x*blockDim.x) {
        float val = 0.f;
        if (idx < OFR) {
            // P1 B-frag: B[k][col=(e,s)]; k 16..25 -> Win[e][s][k-16], k 26 -> b_in
            const int nt = idx >> 9, rem = idx & 511, lane = rem >> 3, j = rem & 7;
            const int k = ((lane >> 4) << 3) + j, col = nt*16 + (lane & 15);
            if (col < 30) {
                const int e = col / 10, s = col - e*10;
                if (k >= 16 && k < 26) val = RD(winv, e*100 + s*10 + (k-16));
                else if (k == 26)      val = RD(binv, e*10 + s);
            }
        } else if (idx < OFH) {
            // P3 A-frags Wr/Wz: A[row=s][k]; k<10 -> W[s][k], 16..25 -> W[s][10+..], 26 -> bias
            const int i2 = idx - OFR;
            const int mt = i2 >> 9, rem = i2 & 511, lane = rem >> 3, j = rem & 7;
            const int k = ((lane >> 4) << 3) + j, s = lane & 15;
            if (s < 10) {
                const void* Wv = mt ? wzv : wrv;
                const void* bv = mt ? bzv : brv;
                if (k < 10)                 val = RD(Wv, s*20 + k);
                else if (k >= 16 && k < 26) val = RD(Wv, s*20 + 10 + (k-16));
                else if (k == 26)           val = RD(bv, s);
            }
        } else if (idx < OFA) {
            const int i2 = idx - OFH;
            const int lane = i2 >> 3, j = i2 & 7;
            const int k = ((lane >> 4) << 3) + j, s = lane & 15;
            if (s < 10) {
                if (k < 10)                 val = RD(whv, s*20 + k);
                else if (k >= 16 && k < 26) val = RD(whv, s*20 + 10 + (k-16));
                else if (k == 26)           val = RD(bhv, s);
            }
        } else {
            // adjacency frag: A[m=node][k=e*72+mm]; zero at pads
            const int i2 = idx - OFA;
            const int w = i2 / 3584, rem = i2 - w*3584;
            const int kt = rem >> 9, r2 = rem & 511, lane = r2 >> 3, j = r2 & 7;
            const int m = w*16 + (lane & 15);
            const int k = kt*32 + ((lane >> 4) << 3) + j;
            const int e = k / 72, mm = k - e*72;
            if (m < NN && e < 3 && mm < NN) val = RD(Av, m*210 + e*70 + mm);
        }
        g_wf[idx] = (_Float16)val;
    }
    #undef RD
}

template<typename T>
__device__ __forceinline__ void run_impl(const void* annv, void* outv, Smem& sm)
{
    const T* ann_g = (const T*)annv;
    T* out_g       = (T*)outv;
    const int lane = threadIdx.x;    // single wave
    const int blk  = blockIdx.x;     // == graph id
    const int q    = lane >> 4;
    const int c    = lane & 15;
    const float* __restrict__ gw = g_w;

    // ---- preload ALL fragments into registers ONCE per block (r0 feature:
    //      adjacency reused 5x from regs; losing this cost +32k cy/block in r2/r3)
    const v8h w1f0 = *(const v8h*)&g_wf[       lane*8];
    const v8h w1f1 = *(const v8h*)&g_wf[512  + lane*8];
    const v8h wrf  = *(const v8h*)&g_wf[OFR  + lane*8];
    const v8h wzf  = *(const v8h*)&g_wf[OFZ  + lane*8];
    const v8h whf  = *(const v8h*)&g_wf[OFH  + lane*8];
    v8h adj[35];
    #pragma unroll
    for (int i = 0; i < 35; ++i)
        adj[i] = *(const v8h*)&g_wf[OFA + i*512 + lane*8];

    // ---- zero LDS (phantom rows/cols MUST be zero)
    {
        const int4 zz = {0,0,0,0};
        int4* z = (int4*)&sm;
        #pragma unroll 4
        for (int i = lane; i < (int)(sizeof(Smem)/16); i += TPB) z[i] = zz;
    }
    __syncthreads();

    // ---- seed: prop[0]=ann at k=16, bias-one at k=26
    for (int n2 = lane; n2 < NN; n2 += TPB) {
        sm.cat[n2*CATN + 16] = (_Float16)(float)ann_g[blk*NN + n2];
        sm.cat[n2*CATN + 26] = (_Float16)1.0f;
    }
    __syncthreads();

    // ---- P1: ins(prop) -> U   (A=cat rows, B=Wstack frags)
    #define PHASE1() do {                                                        \
        _Pragma("unroll")                                                        \
        for (int mt = 0; mt < 5; ++mt) {                                         \
            const v8h af = *(const v8h*)&sm.cat[(mt*16 + c)*CATN + q*8];         \
            const int node0 = mt*16 + q*4;                                       \
            _Pragma("unroll")                                                    \
            for (int nt = 0; nt < 2; ++nt) {                                     \
                v4f acc = {0.f,0.f,0.f,0.f};                                     \
                acc = __builtin_amdgcn_mfma_f32_16x16x32_f16(                    \
                        af, nt ? w1f1 : w1f0, acc, 0,0,0);                       \
                const int colw = nt*16 + c;                                      \
                if (colw < 30 && node0 <= 68) {                                  \
                    const int e = colw / 10, s = colw - e*10;                    \
                    v4h hv = {(_Float16)acc[0],(_Float16)acc[1],                 \
                              (_Float16)acc[2],(_Float16)acc[3]};                \
                    *(v4h*)&sm.U[s*USTR + e*72 + node0] = hv;                    \
                }                                                                \
            }                                                                    \
        }                                                                        \
    } while(0)

    PHASE1();
    __syncthreads();

    #pragma unroll 1
    for (int step = 0; step < STEPS; ++step) {
        // ---- P2 (operand-swapped): a_in^T = U-frag (A) x adj-frag (B)
        //      D[row=s=q*4+r][col=node=mt*16+c] -> ONE packed v4h/v2h store per
        //      lane instead of 4 strided b16 stores + 4 scalar cvts. Adjacency
        //      comes from the register-resident adj[] (NO per-step reloads).
        {
            v8h bfr[7];
            #pragma unroll
            for (int kt = 0; kt < 7; ++kt)
                bfr[kt] = *(const v8h*)&sm.U[c*USTR + q*8 + kt*32];
            #pragma unroll
            for (int mt = 0; mt < 5; ++mt) {
                v4f acc = {0.f,0.f,0.f,0.f};
                #pragma unroll
                for (int kt = 0; kt < 7; ++kt)
                    acc = __builtin_amdgcn_mfma_f32_16x16x32_f16(
                        bfr[kt], adj[mt*7+kt], acc, 0,0,0);
                const int node = mt*16 + c;
                if (node < NN) {
                    const v4h hv = {(_Float16)acc[0],(_Float16)acc[1],
                                    (_Float16)acc[2],(_Float16)acc[3]};
                    _Float16* wp = &sm.cat[node*CATN + q*4];   // s = q*4..q*4+3
                    if (q < 2)       *(v4h*)wp = hv;
                    else if (q == 2) *(v2h*)wp = (v2h){hv[0], hv[1]};   // s=8,9
                }
            }
        }
        __syncthreads();   // a_in visible

        // ---- P3 phase A: r,z + rp-write for ALL 5 node-tiles (5-way ILP),
        //      then ONE fence (was 5 per step in r0). z + old prop carried in
        //      f16 regs (20 VGPRs).
        v4h zgp[5], pgp[5];
        {
            #pragma unroll
            for (int nt = 0; nt < 5; ++nt) {
                const int node = nt*16 + c;
                const v8h bf = *(const v8h*)&sm.cat[node*CATN + q*8];
                v4f ar = {0.f,0.f,0.f,0.f}, az = {0.f,0.f,0.f,0.f};
                ar = __builtin_amdgcn_mfma_f32_16x16x32_f16(wrf, bf, ar, 0,0,0);
                az = __builtin_amdgcn_mfma_f32_16x16x32_f16(wzf, bf, az, 0,0,0);
                const v4h pv = *(const v4h*)&sm.cat[node*CATN + 16 + q*4];
                v4h rp, zh;
                #pragma unroll
                for (int i = 0; i < 4; ++i) {
                    const float p = (float)pv[i];
                    zh[i] = (_Float16)fast_sigmoid(az[i]);
                    rp[i] = (_Float16)(fast_sigmoid(ar[i]) * p);
                }
                zgp[nt] = zh; pgp[nt] = pv;
                if (node < NN) {
                    _Float16* wp = &sm.cat[node*CATN + 16 + q*4];
                    if (q < 2)       *(v4h*)wp = rp;
                    else if (q == 2) *(v2h*)wp = (v2h){rp[0], rp[1]};
                }
            }
        }
        __syncthreads();   // rp visible cross-lane

        // ---- P3 phase B: h + state update for ALL 5 node-tiles
        {
            #pragma unroll
            for (int nt = 0; nt < 5; ++nt) {
                const int node = nt*16 + c;
                const v8h bf2 = *(const v8h*)&sm.cat[node*CATN + q*8];
                v4f ah = {0.f,0.f,0.f,0.f};
                ah = __builtin_amdgcn_mfma_f32_16x16x32_f16(whf, bf2, ah, 0,0,0);
                v4h pn;
                #pragma unroll
                for (int i = 0; i < 4; ++i) {
                    const float hh = fast_tanh(ah[i]);
                    const float p  = (float)pgp[nt][i];
                    const float z  = (float)zgp[nt][i];
                    pn[i] = (_Float16)(p + z*(hh - p));
                }
                if (node < NN) {
                    _Float16* wp = &sm.cat[node*CATN + 16 + q*4];
                    if (q < 2)       *(v4h*)wp = pn;
                    else if (q == 2) *(v2h*)wp = (v2h){pn[0], pn[1]};
                }
            }
        }
        __syncthreads();   // new prop visible

        // ---- P1 for next step
        if (step < STEPS-1) {
            PHASE1();
            __syncthreads();
        }
    }
    #undef PHASE1

    // ---- epilogue: one output per node
    for (int n2 = lane; n2 < NN; n2 += TPB) {
        const _Float16* pc = &sm.cat[n2*CATN + 16];
        const v8h p8 = *(const v8h*)pc;
        const v2h p2 = *(const v2h*)(pc + 8);
        float pr[10];
        #pragma unroll
        for (int i = 0; i < 8; ++i) pr[i] = (float)p8[i];
        pr[8] = (float)p2[0]; pr[9] = (float)p2[1];
        const float av = (float)ann_g[blk*NN + n2];
        float o = gw[PBO2];
        #pragma unroll
        for (int s = 0; s < 10; ++s) {
            const float* wr_ = &gw[PWO1 + s*12];
            float acc = wr_[11] + wr_[10]*av;
            #pragma unroll
            for (int d = 0; d < 10; ++d) acc += pr[d]*wr_[d];
            o += fast_tanh(acc) * gw[PWO2 + s];
        }
        out_g[blk*NN + n2] = (T)o;
    }
}

// min-waves=2 -> 256-VGPR cap; r0 landed at 120 VGPR under this bound with the
// same preload set. r1 lesson: min-waves=4 squeezes to the 64-VGPR tier and
// SPILLS (+23MB scratch). Tripwire: WRITE_SIZE >> 4.9MB => spill => drop the
// zgp/pgp batching next round.
__global__ __launch_bounds__(TPB, 2)
void ggnn_kernel(const void* annv, void* outv)
{
    __shared__ Smem sm;
    if (g_flag)
        run_impl<__hip_bfloat16>(annv, outv, sm);
    else
        run_impl<float>(annv, outv, sm);
}

extern "C" void kernel_launch(void* const* d_in, const int* in_sizes, int n_in,
                              void* d_out, int out_size, void* d_ws, size_t ws_size,
                              hipStream_t stream) {
    (void)in_sizes; (void)n_in; (void)out_size; (void)d_ws; (void)ws_size;
    hipLaunchKernelGGL(prep_kernel, dim3(PREPB), dim3(256), 0, stream,
        d_in[0], d_in[1], d_in[2], d_in[3], d_in[4], d_in[5], d_in[6],
        d_in[7], d_in[8], d_in[9], d_in[10], d_in[11], d_in[12], d_in[13]);
    hipLaunchKernelGGL(ggnn_kernel, dim3(NBLK), dim3(TPB), 0, stream,
        d_in[0], d_out);
}